// Round 3
// baseline (534.762 us; speedup 1.0000x reference)
//
#include <hip/hip_runtime.h>

#define IN_DIM 512
#define NBATCH 8192
#define HSTR 136     // old kernels' Hsh stride (u16)

// ---- 8-phase-lite kernel geometry ----
#define BM8 256
#define BNT 128          // cols per nt  (4 nts cover hidden=512)
#define BK8 32
#define A_SLOT_U16 8192      // [256][32] bf16
#define B_SLOT_U16 4096      // [128][32] bf16
#define B_BASE_U16 24576     // 3 A slots
#define H_BASE_U16 36864     // 3 B slots end
#define H_STRIDE   132       // [256][132] u16
#define LDS_U16_TOTAL (H_BASE_U16 + 256 * H_STRIDE)   // 70,656 u16 = 141,312 B

typedef short s16x8 __attribute__((ext_vector_type(8)));
typedef float f32x4 __attribute__((ext_vector_type(4)));

__device__ __forceinline__ unsigned short f2bf(float f) {
    union { float f; unsigned int u; } c;
    c.f = f;
    unsigned int u = c.u;
    u += 0x7fffu + ((u >> 16) & 1u);   // round-to-nearest-even
    return (unsigned short)(u >> 16);
}

__device__ __forceinline__ void gload16(const unsigned short* g, unsigned short* l) {
    __builtin_amdgcn_global_load_lds(
        (const __attribute__((address_space(1))) void*)g,
        (__attribute__((address_space(3))) void*)l,
        16, 0, 0);
}

// ---------------- preprocessing: f32 -> bf16 (+ transpose for Wx, Wp) ----------------

__global__ __launch_bounds__(256)
void conv_inp(const float* __restrict__ in, unsigned short* __restrict__ out) {
    int i = (blockIdx.x * 256 + threadIdx.x) * 8;
    float4 a = *(const float4*)&in[i];
    float4 b = *(const float4*)&in[i + 4];
    union { unsigned short u[8]; s16x8 v; } r;
    r.u[0] = f2bf(a.x); r.u[1] = f2bf(a.y); r.u[2] = f2bf(a.z); r.u[3] = f2bf(a.w);
    r.u[4] = f2bf(b.x); r.u[5] = f2bf(b.y); r.u[6] = f2bf(b.z); r.u[7] = f2bf(b.w);
    *(s16x8*)&out[i] = r.v;
}

// WxT[j][col][k] = bf16(Wx[j][k][col]) via 64x64 LDS tile transpose
__global__ __launch_bounds__(256)
void conv_wxT(const float* __restrict__ Wx, unsigned short* __restrict__ WxT) {
    __shared__ unsigned short T[64][80];
    int j  = blockIdx.y;
    int tr = blockIdx.x >> 3;   // k-tile
    int tc = blockIdx.x & 7;    // col-tile
    const float* src = Wx + (size_t)j * IN_DIM * IN_DIM;
    unsigned short* dst = WxT + (size_t)j * IN_DIM * IN_DIM;
    int tid = threadIdx.x;
    int k  = tid >> 2;
    int c0 = (tid & 3) * 16;
    for (int u = 0; u < 16; u += 4) {
        float4 v = *(const float4*)&src[(size_t)(tr * 64 + k) * IN_DIM + tc * 64 + c0 + u];
        T[c0 + u + 0][k] = f2bf(v.x);
        T[c0 + u + 1][k] = f2bf(v.y);
        T[c0 + u + 2][k] = f2bf(v.z);
        T[c0 + u + 3][k] = f2bf(v.w);
    }
    __syncthreads();
    int c  = tid >> 2;
    int k0 = (tid & 3) * 16;
    for (int u = 0; u < 16; u += 8) {
        s16x8 v = *(const s16x8*)&T[c][k0 + u];
        *(s16x8*)&dst[(size_t)(tc * 64 + c) * IN_DIM + tr * 64 + k0 + u] = v;
    }
}

// WpT[j][w][k] = bf16(Wp[j][k][w])
__global__ __launch_bounds__(256)
void conv_wpT(const float* __restrict__ Wp, unsigned short* __restrict__ WpT) {
    int j = blockIdx.x;
    const float* src = Wp + (size_t)j * IN_DIM * 8;
    unsigned short* dst = WpT + (size_t)j * IN_DIM * 8;
    for (int k = threadIdx.x; k < IN_DIM; k += 256)
        for (int w = 0; w < 8; ++w)
            dst[w * IN_DIM + k] = f2bf(src[k * 8 + w]);
}

// ---------------- phase-pipelined fused level kernel (256x128-tile, 8 waves) ----------------
__global__ __launch_bounds__(512, 2)
void level_8ph(const unsigned short* __restrict__ inpB,   // [8192][512] bf16
               const unsigned short* __restrict__ WxT,    // [n][512 col][512 k] bf16
               const float* __restrict__ bx,
               const unsigned short* __restrict__ WpT,    // [n][8][512] bf16
               const float* __restrict__ bp,
               const float* __restrict__ parent,
               int pstride, int poff, int invert_parent,
               float* __restrict__ outp, int ostride)
{
    extern __shared__ __align__(16) unsigned short lds[];

    const int tid  = threadIdx.x;
    const int lane = tid & 63;
    const int wid  = tid >> 6;        // 0..7
    const int wr   = wid >> 1;        // 0..3 : wave row 64-block
    const int wc   = wid & 1;         // 0..1 : wave col 64-block
    const int j    = blockIdx.y;
    const int rowBase = blockIdx.x * BM8;
    const int lr   = lane & 15;
    const int grp  = lane >> 4;       // 0..3
    const int kg8  = grp * 8;
    const int rg   = grp * 4;

    const unsigned short* WxTj = WxT + (size_t)j * IN_DIM * IN_DIM;
    const unsigned short* WpTj = WpT + (size_t)j * IN_DIM * 8;

    // staging source geometry (per thread: 2 A loads + 1 B load per tile)
    const int srcRow = tid >> 2;              // 0..127
    const int srcK   = (tid & 3) * 8;
    const unsigned short* gA  = inpB + (size_t)(rowBase + srcRow) * IN_DIM + srcK;
    const unsigned short* gB0 = WxTj + (size_t)srcRow * IN_DIM + srcK;
    unsigned short* ldsW = lds + wid * 512;   // wave-uniform dest base (+ lane*16B implicit)

    auto STAGE = [&](int g2, int sl_) {
        int kt  = (g2 & 15) * BK8;
        int nt2 = g2 >> 4;
        const unsigned short* a = gA + kt;
        gload16(a,                    ldsW + sl_ * A_SLOT_U16);
        gload16(a + 128 * IN_DIM,     ldsW + sl_ * A_SLOT_U16 + 4096);
        gload16(gB0 + (size_t)nt2 * BNT * IN_DIM + kt,
                                      ldsW + B_BASE_U16 + sl_ * B_SLOT_U16);
    };

    f32x4 acc[4][4] = {};
    f32x4 acc2[2]  = {};

    // prologue: tiles 0,1 into slots 0,1; wait tile0
    STAGE(0, 0);
    STAGE(1, 1);
    asm volatile("s_waitcnt vmcnt(3)" ::: "memory");
    __builtin_amdgcn_s_barrier();

    int sl = 0, sl2 = 2;
    for (int g = 0; g < 64; ++g) {
        // ---- frag reads from slot sl (conflict-free: contiguous 1KB per wave) ----
        const unsigned short* As = lds + sl * A_SLOT_U16 + (wr * 64 + lr) * BK8 + kg8;
        const unsigned short* Bs = lds + B_BASE_U16 + sl * B_SLOT_U16 + (wc * 64 + lr) * BK8 + kg8;
        s16x8 af[4], bf[4];
        #pragma unroll
        for (int mt = 0; mt < 4; ++mt) af[mt] = *(const s16x8*)(As + mt * 16 * BK8);
        #pragma unroll
        for (int nn = 0; nn < 4; ++nn) bf[nn] = *(const s16x8*)(Bs + nn * 16 * BK8);

        // ---- prefetch tile g+2 into just-freed slot ----
        bool staged = (g + 2 < 64);
        if (staged) STAGE(g + 2, sl2);

        __builtin_amdgcn_s_barrier();

        __builtin_amdgcn_s_setprio(1);
        #pragma unroll
        for (int mt = 0; mt < 4; ++mt)
            #pragma unroll
            for (int nn = 0; nn < 4; ++nn)
                acc[mt][nn] = __builtin_amdgcn_mfma_f32_16x16x32_bf16(
                    af[mt], bf[nn], acc[mt][nn], 0, 0, 0);
        __builtin_amdgcn_s_setprio(0);

        // counted wait: tile g+1 landed; tile g+2's 3 loads stay in flight
        if (staged) asm volatile("s_waitcnt vmcnt(3)" ::: "memory");
        else        asm volatile("s_waitcnt vmcnt(0)" ::: "memory");
        __builtin_amdgcn_s_barrier();

        if ((g & 15) == 15) {
            int nt = g >> 4;
            // ---- h = relu(acc + bx) -> Hsh (bf16), all 8 waves, conflict-free stride ----
            #pragma unroll
            for (int nn = 0; nn < 4; ++nn) {
                int ncol = wc * 64 + nn * 16 + lr;
                float bxv = bx[(size_t)j * IN_DIM + nt * BNT + ncol];
                #pragma unroll
                for (int mt = 0; mt < 4; ++mt)
                    #pragma unroll
                    for (int v = 0; v < 4; ++v) {
                        float h = acc[mt][nn][v] + bxv;
                        h = h > 0.f ? h : 0.f;
                        lds[H_BASE_U16 + (wr * 64 + mt * 16 + rg + v) * H_STRIDE + ncol] = f2bf(h);
                        acc[mt][nn][v] = 0.f;
                    }
            }
            // publish Hsh writes without draining vmcnt (prefetch stays in flight)
            asm volatile("s_waitcnt lgkmcnt(0)" ::: "memory");
            __builtin_amdgcn_s_barrier();
            // ---- stage-2: logits += Hsh @ WpT^T  (wave wid: rows wid*32..+32) ----
            #pragma unroll
            for (int k2 = 0; k2 < 4; ++k2) {
                s16x8 b2 = *(const s16x8*)(WpTj + (size_t)(lr & 7) * IN_DIM + nt * BNT + k2 * 32 + kg8);
                #pragma unroll
                for (int m2 = 0; m2 < 2; ++m2) {
                    s16x8 a2 = *(const s16x8*)&lds[H_BASE_U16 + (wid * 32 + m2 * 16 + lr) * H_STRIDE + k2 * 32 + kg8];
                    acc2[m2] = __builtin_amdgcn_mfma_f32_16x16x32_bf16(a2, b2, acc2[m2], 0, 0, 0);
                }
            }
            // next Hsh write is 16 barriered phases away -> no extra barrier needed
        }
        sl  = (sl  == 2) ? 0 : sl  + 1;
        sl2 = (sl2 == 2) ? 0 : sl2 + 1;
    }

    // ---- softmax over 8 cols + parent scale + store ----
    bool valid = lr < 8;
    float bpv = valid ? bp[(size_t)j * 8 + lr] : 0.f;
    #pragma unroll
    for (int m2 = 0; m2 < 2; ++m2) {
        #pragma unroll
        for (int v = 0; v < 4; ++v) {
            float x = acc2[m2][v] + bpv;
            float mx = x;
            for (int d = 1; d < 8; d <<= 1)
                mx = fmaxf(mx, __shfl_xor(mx, d, 64));
            float e = __expf(x - mx);
            float s = e;
            for (int d = 1; d < 8; d <<= 1)
                s += __shfl_xor(s, d, 64);
            float p = e / s;
            int gb = rowBase + wid * 32 + m2 * 16 + rg + v;
            float pv = invert_parent ? (1.f - parent[(size_t)gb * pstride + poff])
                                     : parent[(size_t)gb * pstride + j];
            if (valid)
                outp[(size_t)gb * ostride + j * 8 + lr] = p * pv;
        }
    }
}

// ---------------- round-2 fused level kernel (proven; used for level 0 + fallback) ----------------
__global__ __launch_bounds__(256, 2)
void level_fast(const unsigned short* __restrict__ inpB,
                const unsigned short* __restrict__ WxT,
                const float* __restrict__ bx,
                const unsigned short* __restrict__ WpT,
                const float* __restrict__ bp,
                const float* __restrict__ parent,
                int pstride, int poff, int invert_parent,
                float* __restrict__ outp, int ostride)
{
    __shared__ __align__(16) unsigned short lds[128 * HSTR];

    const int tid  = threadIdx.x;
    const int lane = tid & 63;
    const int wv   = tid >> 6;
    const int j    = blockIdx.y;
    const int rowBase = blockIdx.x * 128;
    const int lr  = lane & 15;
    const int kg8 = (lane >> 4) * 8;
    const int rg  = (lane >> 4) * 4;
    const int wm  = (wv & 1) * 64;
    const int wn  = (wv >> 1) * 64;

    const unsigned short* WxTj = WxT + (size_t)j * IN_DIM * IN_DIM;
    const unsigned short* WpTj = WpT + (size_t)j * IN_DIM * 8;

    const int srow  = wv * 32 + (lane >> 2);
    const int sslot = (lane & 3) * 8;

    f32x4 acc2[2] = {};

    for (int nt = 0; nt < 4; ++nt) {
        f32x4 acc[4][4] = {};
        for (int k0 = 0; k0 < IN_DIM; k0 += 32) {
            __syncthreads();
            {
                const unsigned short* ga = inpB + (size_t)(rowBase + srow) * IN_DIM + k0 + sslot;
                const unsigned short* gb = WxTj + (size_t)(nt * 128 + srow) * IN_DIM + k0 + sslot;
                gload16(ga,                &lds[wv * 1024]);
                gload16(ga + 16 * IN_DIM,  &lds[wv * 1024 + 512]);
                gload16(gb,                &lds[4096 + wv * 1024]);
                gload16(gb + 16 * IN_DIM,  &lds[4096 + wv * 1024 + 512]);
            }
            __syncthreads();
            s16x8 af[4], bfr[4];
            for (int mt = 0; mt < 4; ++mt)
                af[mt] = *(const s16x8*)&lds[(wm + mt * 16 + lr) * 32 + kg8];
            for (int nn = 0; nn < 4; ++nn)
                bfr[nn] = *(const s16x8*)&lds[4096 + (wn + nn * 16 + lr) * 32 + kg8];
            for (int mt = 0; mt < 4; ++mt)
                for (int nn = 0; nn < 4; ++nn)
                    acc[mt][nn] = __builtin_amdgcn_mfma_f32_16x16x32_bf16(
                        af[mt], bfr[nn], acc[mt][nn], 0, 0, 0);
        }
        __syncthreads();
        for (int nn = 0; nn < 4; ++nn) {
            int ncol = wn + nn * 16 + lr;
            float bxv = bx[(size_t)j * IN_DIM + nt * 128 + ncol];
            for (int mt = 0; mt < 4; ++mt)
                for (int v = 0; v < 4; ++v) {
                    float h = acc[mt][nn][v] + bxv;
                    h = h > 0.f ? h : 0.f;
                    lds[(wm + mt * 16 + rg + v) * HSTR + ncol] = f2bf(h);
                }
        }
        __syncthreads();
        for (int k2 = 0; k2 < 4; ++k2) {
            int jw = lr & 7;
            s16x8 b2 = *(const s16x8*)(WpTj + jw * IN_DIM + nt * 128 + k2 * 32 + kg8);
            for (int m2 = 0; m2 < 2; ++m2) {
                s16x8 a2 = *(const s16x8*)&lds[(wv * 32 + m2 * 16 + lr) * HSTR + k2 * 32 + kg8];
                acc2[m2] = __builtin_amdgcn_mfma_f32_16x16x32_bf16(a2, b2, acc2[m2], 0, 0, 0);
            }
        }
    }

    bool valid = lr < 8;
    float bpv = valid ? bp[(size_t)j * 8 + lr] : 0.f;
    for (int m2 = 0; m2 < 2; ++m2) {
        for (int v = 0; v < 4; ++v) {
            float x = acc2[m2][v] + bpv;
            float mx = x;
            for (int d = 1; d < 8; d <<= 1)
                mx = fmaxf(mx, __shfl_xor(mx, d, 64));
            float e = __expf(x - mx);
            float s = e;
            for (int d = 1; d < 8; d <<= 1)
                s += __shfl_xor(s, d, 64);
            float p = e / s;
            int gb = rowBase + wv * 32 + m2 * 16 + rg + v;
            float pv = invert_parent ? (1.f - parent[(size_t)gb * pstride + poff])
                                     : parent[(size_t)gb * pstride + j];
            if (valid)
                outp[(size_t)gb * ostride + j * 8 + lr] = p * pv;
        }
    }
}

// ---------------- fallback (f32-direct) level kernel, used if ws too small ----------------
__global__ __launch_bounds__(256, 2)
void level_ref(const float* __restrict__ inp,
               const float* __restrict__ Wx,
               const float* __restrict__ bx,
               const float* __restrict__ Wp,
               const float* __restrict__ bp,
               const float* __restrict__ parent,
               int pstride, int poff, int invert_parent,
               float* __restrict__ outp, int ostride)
{
    __shared__ __align__(16) unsigned short Ash[128][40];
    __shared__ __align__(16) unsigned short Bsh[128][40];
    __shared__ __align__(16) unsigned short Hsh[128][HSTR];
    __shared__ __align__(16) unsigned short WpSh[8][IN_DIM];

    const int tid  = threadIdx.x;
    const int lane = tid & 63;
    const int wv   = tid >> 6;
    const int j    = blockIdx.y;
    const int rowBase = blockIdx.x * 128;
    const int lr = lane & 15;
    const int kg = (lane >> 4) * 8;
    const int rg = (lane >> 4) * 4;
    const int wm = (wv & 1) * 64;
    const int wn = (wv >> 1) * 64;

    const float* WxJ = Wx + (size_t)j * IN_DIM * IN_DIM;
    const float* WpJ = Wp + (size_t)j * IN_DIM * 8;

    for (int i = tid; i < IN_DIM * 2; i += 256) {
        int k  = i >> 1;
        int w4 = (i & 1) * 4;
        float4 v = *(const float4*)&WpJ[k * 8 + w4];
        WpSh[w4 + 0][k] = f2bf(v.x);
        WpSh[w4 + 1][k] = f2bf(v.y);
        WpSh[w4 + 2][k] = f2bf(v.z);
        WpSh[w4 + 3][k] = f2bf(v.w);
    }

    f32x4 acc2[2] = {};

    for (int nt = 0; nt < 4; ++nt) {
        f32x4 acc[4][4] = {};
        for (int k0 = 0; k0 < IN_DIM; k0 += 32) {
            __syncthreads();
            {
                int kk4 = (tid & 7) * 4;
                int rb  = tid >> 3;
                for (int it = 0; it < 4; ++it) {
                    int r = rb + it * 32;
                    float4 v = *(const float4*)&inp[(size_t)(rowBase + r) * IN_DIM + k0 + kk4];
                    unsigned short* dst = &Ash[r][kk4];
                    dst[0] = f2bf(v.x); dst[1] = f2bf(v.y);
                    dst[2] = f2bf(v.z); dst[3] = f2bf(v.w);
                }
            }
            {
                int n4 = (tid & 31) * 4;
                int kb = tid >> 5;
                for (int it = 0; it < 4; ++it) {
                    int kk = kb + it * 8;
                    float4 v = *(const float4*)&WxJ[(size_t)(k0 + kk) * IN_DIM + nt * 128 + n4];
                    Bsh[n4 + 0][kk] = f2bf(v.x);
                    Bsh[n4 + 1][kk] = f2bf(v.y);
                    Bsh[n4 + 2][kk] = f2bf(v.z);
                    Bsh[n4 + 3][kk] = f2bf(v.w);
                }
            }
            __syncthreads();
            s16x8 af[4], bfr[4];
            for (int mt = 0; mt < 4; ++mt)
                af[mt] = *(const s16x8*)&Ash[wm + mt * 16 + lr][kg];
            for (int nn = 0; nn < 4; ++nn)
                bfr[nn] = *(const s16x8*)&Bsh[wn + nn * 16 + lr][kg];
            for (int mt = 0; mt < 4; ++mt)
                for (int nn = 0; nn < 4; ++nn)
                    acc[mt][nn] = __builtin_amdgcn_mfma_f32_16x16x32_bf16(
                        af[mt], bfr[nn], acc[mt][nn], 0, 0, 0);
        }
        __syncthreads();
        for (int nn = 0; nn < 4; ++nn) {
            int ncol = wn + nn * 16 + lr;
            float bxv = bx[(size_t)j * IN_DIM + nt * 128 + ncol];
            for (int mt = 0; mt < 4; ++mt)
                for (int v = 0; v < 4; ++v) {
                    float h = acc[mt][nn][v] + bxv;
                    h = h > 0.f ? h : 0.f;
                    Hsh[wm + mt * 16 + rg + v][ncol] = f2bf(h);
                }
        }
        __syncthreads();
        {
            s16x8 zero = {};
            for (int k2 = 0; k2 < 128; k2 += 32) {
                s16x8 b2 = (lr < 8) ? *(const s16x8*)&WpSh[lr][nt * 128 + k2 + kg] : zero;
                for (int m2 = 0; m2 < 2; ++m2) {
                    s16x8 a2 = *(const s16x8*)&Hsh[wv * 32 + m2 * 16 + lr][k2 + kg];
                    acc2[m2] = __builtin_amdgcn_mfma_f32_16x16x32_bf16(a2, b2, acc2[m2], 0, 0, 0);
                }
            }
        }
    }

    bool valid = lr < 8;
    float bpv = valid ? bp[(size_t)j * 8 + lr] : 0.f;
    for (int m2 = 0; m2 < 2; ++m2) {
        for (int v = 0; v < 4; ++v) {
            float x = acc2[m2][v] + bpv;
            float mx = x;
            for (int d = 1; d < 8; d <<= 1)
                mx = fmaxf(mx, __shfl_xor(mx, d, 64));
            float e = __expf(x - mx);
            float s = e;
            for (int d = 1; d < 8; d <<= 1)
                s += __shfl_xor(s, d, 64);
            float p = e / s;
            int gb = rowBase + wv * 32 + m2 * 16 + rg + v;
            float pv = invert_parent ? (1.f - parent[(size_t)gb * pstride + poff])
                                     : parent[(size_t)gb * pstride + j];
            if (valid)
                outp[(size_t)gb * ostride + j * 8 + lr] = p * pv;
        }
    }
}

// got_event head
__global__ __launch_bounds__(256)
void head_kernel(const float* __restrict__ inp,
                 const float* __restrict__ We,
                 const float* __restrict__ be,
                 float* __restrict__ out)
{
    int row  = blockIdx.x * 4 + (threadIdx.x >> 6);
    int lane = threadIdx.x & 63;
    const float* ip = inp + (size_t)row * IN_DIM;
    float4 a0 = *(const float4*)&ip[lane * 8];
    float4 a1 = *(const float4*)&ip[lane * 8 + 4];
    float4 w0 = *(const float4*)&We[lane * 8];
    float4 w1 = *(const float4*)&We[lane * 8 + 4];
    float s = a0.x*w0.x + a0.y*w0.y + a0.z*w0.z + a0.w*w0.w
            + a1.x*w1.x + a1.y*w1.y + a1.z*w1.z + a1.w*w1.w;
    for (int d = 1; d < 64; d <<= 1)
        s += __shfl_xor(s, d, 64);
    if (lane == 0) {
        float ge = 1.f / (1.f + __expf(-(s + be[0])));
        float og = 1.f - ge;
        out[(size_t)row * 9 + 8] = og;
        out[(size_t)(NBATCH * 9) + (size_t)row * 65 + 64] = og;
        out[(size_t)(NBATCH * 9 + NBATCH * 65) + (size_t)row * 513 + 512] = og;
    }
}

extern "C" void kernel_launch(void* const* d_in, const int* in_sizes, int n_in,
                              void* d_out, int out_size, void* d_ws, size_t ws_size,
                              hipStream_t stream) {
    const float* inp = (const float*)d_in[0];
    const float* Wx0 = (const float*)d_in[1];
    const float* bx0 = (const float*)d_in[2];
    const float* Wp0 = (const float*)d_in[3];
    const float* bp0 = (const float*)d_in[4];
    const float* Wx1 = (const float*)d_in[5];
    const float* bx1 = (const float*)d_in[6];
    const float* Wp1 = (const float*)d_in[7];
    const float* bp1 = (const float*)d_in[8];
    const float* Wx2 = (const float*)d_in[9];
    const float* bx2 = (const float*)d_in[10];
    const float* Wp2 = (const float*)d_in[11];
    const float* bp2 = (const float*)d_in[12];
    const float* We  = (const float*)d_in[13];
    const float* be  = (const float*)d_in[14];
    float* out = (float*)d_out;

    const size_t OUT1 = (size_t)NBATCH * 9;
    const size_t OUT2 = OUT1 + (size_t)NBATCH * 65;

    const size_t INP_E = (size_t)NBATCH * IN_DIM;
    const size_t WX_E  = (size_t)IN_DIM * IN_DIM;
    const size_t WP_E  = (size_t)IN_DIM * 8;
    const size_t NEED  = 2 * (INP_E + 73 * WX_E + 73 * WP_E);

    head_kernel<<<NBATCH / 4, 256, 0, stream>>>(inp, We, be, out);

    dim3 blk(256);
    if (ws_size >= NEED) {
        unsigned short* inpB   = (unsigned short*)d_ws;
        unsigned short* WxTall = inpB + INP_E;
        unsigned short* WpTall = WxTall + 73 * WX_E;

        conv_inp<<<NBATCH * IN_DIM / (256 * 8), 256, 0, stream>>>(inp, inpB);
        conv_wxT<<<dim3(64, 1),  blk, 0, stream>>>(Wx0, WxTall);
        conv_wxT<<<dim3(64, 8),  blk, 0, stream>>>(Wx1, WxTall + 1 * WX_E);
        conv_wxT<<<dim3(64, 64), blk, 0, stream>>>(Wx2, WxTall + 9 * WX_E);
        conv_wpT<<<1,  blk, 0, stream>>>(Wp0, WpTall);
        conv_wpT<<<8,  blk, 0, stream>>>(Wp1, WpTall + 1 * WP_E);
        conv_wpT<<<64, blk, 0, stream>>>(Wp2, WpTall + 9 * WP_E);

        // level 0 (tiny grid): proven 128-row kernel
        level_fast<<<dim3(NBATCH / 128, 1), blk, 0, stream>>>(
            inpB, WxTall, bx0, WpTall, bp0, out, 9, 8, 1, out, 9);

        const int LDS_BYTES = LDS_U16_TOTAL * 2;   // 141,312 B
        hipError_t rc = hipFuncSetAttribute((const void*)level_8ph,
                                            hipFuncAttributeMaxDynamicSharedMemorySize,
                                            LDS_BYTES);
        if (rc == hipSuccess) {
            level_8ph<<<dim3(NBATCH / BM8, 8), dim3(512), LDS_BYTES, stream>>>(
                inpB, WxTall + 1 * WX_E, bx1, WpTall + 1 * WP_E, bp1,
                out, 9, 0, 0, out + OUT1, 65);
            level_8ph<<<dim3(NBATCH / BM8, 64), dim3(512), LDS_BYTES, stream>>>(
                inpB, WxTall + 9 * WX_E, bx2, WpTall + 9 * WP_E, bp2,
                out + OUT1, 65, 0, 0, out + OUT2, 513);
        } else {
            level_fast<<<dim3(NBATCH / 128, 8), blk, 0, stream>>>(
                inpB, WxTall + 1 * WX_E, bx1, WpTall + 1 * WP_E, bp1,
                out, 9, 0, 0, out + OUT1, 65);
            level_fast<<<dim3(NBATCH / 128, 64), blk, 0, stream>>>(
                inpB, WxTall + 9 * WX_E, bx2, WpTall + 9 * WP_E, bp2,
                out + OUT1, 65, 0, 0, out + OUT2, 513);
        }
    } else {
        level_ref<<<dim3(NBATCH / 128, 1), blk, 0, stream>>>(
            inp, Wx0, bx0, Wp0, bp0, out, 9, 8, 1, out, 9);
        level_ref<<<dim3(NBATCH / 128, 8), blk, 0, stream>>>(
            inp, Wx1, bx1, Wp1, bp1, out, 9, 0, 0, out + OUT1, 65);
        level_ref<<<dim3(NBATCH / 128, 64), blk, 0, stream>>>(
            inp, Wx2, bx2, Wp2, bp2, out + OUT1, 65, 0, 0, out + OUT2, 513);
    }
}